// Round 6
// baseline (482.150 us; speedup 1.0000x reference)
//
#include <hip/hip_runtime.h>

typedef __bf16 bf16;
typedef __bf16 bf16x4 __attribute__((ext_vector_type(4)));
typedef __bf16 bf16x8 __attribute__((ext_vector_type(8)));
typedef float  f32x4  __attribute__((ext_vector_type(4)));

// Problem constants
#define NB    16384      // batch
#define NOBS  568
#define NH    256
#define NAG   19         // N_OTHER

// ws byte offsets (all 16B aligned)
#define OFF_WT_MU    0u          // FLAT [256][576] bf16 (zself stages via LDS)
#define OFF_WT_VAR   294912u     // FLAT [256][576]
#define OFF_WT_SELF  589824u     // FLAT [256][64]
#define OFF_WT_OTHER 622592u     // [256][32]  (chunk-major == flat at K=32)
#define OFF_WT_Q     638976u     // CHUNK-MAJOR [8][256][32] (chunk-8 overflow -> WT_K)
#define OFF_WT_K     770048u     // CHUNK-MAJOR [8][256][32] (chunk-8 overflow -> V1)
#define OFF_WT_V1    901120u     // CHUNK-MAJOR [8][256][32] (chunk-8 overflow -> V2)
#define OFF_WT_V2    1032192u    // CHUNK-MAJOR [8][256][32] (chunk-8 overflow -> A1)
#define OFF_WT_A1    1163264u    // CHUNK-MAJOR [8][256][32]
#define OFF_WT_A2    1294336u    // CHUNK-MAJOR [8][256][32] (chunk-8 overflow -> Z, allocated)
#define OFF_Z        1425408u    // [16384][256] bf16
#define OFF_SELF     9814016u
#define OFF_Q        18202624u   // UNUSED since round 16
#define OFF_SV       26591232u   // UNUSED since round 16
#define OFF_H        34979840u   // UNUSED since round 16

static __device__ __forceinline__ unsigned short bfbits(float v) {
  bf16 b = (bf16)v;
  union { bf16 b; unsigned short u; } cvt; cvt.b = b; return cvt.u;
}

// ---------------------------------------------------------------------------
// Weight prep (unchanged from round 15).
// ---------------------------------------------------------------------------
__global__ __launch_bounds__(256) void wprep(
    const float* __restrict__ Wmu, const float* __restrict__ Wvar,
    const float* __restrict__ Wself, const float* __restrict__ Wother,
    const float* __restrict__ Wq, const float* __restrict__ Wk,
    const float* __restrict__ Wv, const float* __restrict__ Wa, char* wsb)
{
  const float* src; bf16* dst; int K, Kp; bool chunked = false;
  switch (blockIdx.y) {
    case 0: src = Wmu;        dst = (bf16*)(wsb + OFF_WT_MU);    K = 568; Kp = 576; break;
    case 1: src = Wvar;       dst = (bf16*)(wsb + OFF_WT_VAR);   K = 568; Kp = 576; break;
    case 2: src = Wself;      dst = (bf16*)(wsb + OFF_WT_SELF);  K = 36;  Kp = 64;  break;
    case 3: src = Wother;     dst = (bf16*)(wsb + OFF_WT_OTHER); K = 28;  Kp = 32;  break;
    case 4: src = Wq;         dst = (bf16*)(wsb + OFF_WT_Q);     K = 256; Kp = 256; chunked = true; break;
    case 5: src = Wk;         dst = (bf16*)(wsb + OFF_WT_K);     K = 256; Kp = 256; chunked = true; break;
    case 6: src = Wv;         dst = (bf16*)(wsb + OFF_WT_V1);    K = 256; Kp = 256; chunked = true; break;
    case 7: src = Wv + 65536; dst = (bf16*)(wsb + OFF_WT_V2);    K = 256; Kp = 256; chunked = true; break;
    case 8: src = Wa;         dst = (bf16*)(wsb + OFF_WT_A1);    K = 256; Kp = 256; chunked = true; break;
    default: src = Wa + 65536; dst = (bf16*)(wsb + OFF_WT_A2);   K = 256; Kp = 256; chunked = true; break;
  }
  int total = 256 * Kp;
  if (chunked) {
    for (int i = blockIdx.x * 256 + threadIdx.x; i < total; i += gridDim.x * 256) {
      int ch = i >> 13, n = (i >> 5) & 255, kk = i & 31;
      int k = ch * 32 + kk;
      dst[i] = (bf16)src[k * 256 + n];
    }
  } else {
    for (int i = blockIdx.x * 256 + threadIdx.x; i < total; i += gridDim.x * 256) {
      int n = i / Kp, k = i - n * Kp;
      dst[i] = (k < K) ? (bf16)src[k * 256 + n] : (bf16)0.f;
    }
  }
}

// ---------------------------------------------------------------------------
// Merged z + self GEMM (unchanged, proven).
// ---------------------------------------------------------------------------
__global__ __launch_bounds__(256, 3) void gemm_zself(
    const float* __restrict__ x,
    const bf16* __restrict__ WtMu, const bf16* __restrict__ WtVar,
    const bf16* __restrict__ WtSelf,
    const float* __restrict__ b_mu, const float* __restrict__ b_var,
    const float* __restrict__ b_self, const float* __restrict__ eps,
    bf16* __restrict__ zout, bf16* __restrict__ selfout)
{
  __shared__ bf16 ldsA[64 * 40];
  __shared__ bf16 ldsB[128 * 40];
  __shared__ bf16 ldsB2[128 * 40];

  const int tid = threadIdx.x;
  const int wave = tid >> 6;
  const int lane = tid & 63;
  const int quad = lane >> 4;
  const int m = lane & 15;
  const int rowbase = blockIdx.x * 64;
  const int colbase = (blockIdx.y & 1) * 128;
  const bool isZ = blockIdx.y < 2;
  const int K = isZ ? 576 : 64;
  const bf16* __restrict__ Wt = isZ ? WtMu : WtSelf;
  const float* __restrict__ bias = isZ ? b_mu : b_self;

  f32x4 acc[8], accB[8];
  const f32x4 z4 = {0.f, 0.f, 0.f, 0.f};
#pragma unroll
  for (int ct = 0; ct < 8; ++ct) { acc[ct] = z4; accB[ct] = z4; }

  for (int kc = 0; kc < K; kc += 32) {
    __syncthreads();
    {
#pragma unroll
      for (int it = 0; it < 2; ++it) {
        int p = tid + 256 * it;          // 512 float4 segments (64 rows x 8)
        int r = p >> 3, fs = p & 7;
        int k = kc + fs * 4;
        const float* src = x + (size_t)(rowbase + r) * 568 + k;
        float v0, v1, v2, v3;
        if (k + 4 <= 568) {
          float4 v = *(const float4*)src;
          v0 = v.x; v1 = v.y; v2 = v.z; v3 = v.w;
        } else {
          v0 = (k + 0 < 568) ? src[0] : 0.f;
          v1 = (k + 1 < 568) ? src[1] : 0.f;
          v2 = (k + 2 < 568) ? src[2] : 0.f;
          v3 = (k + 3 < 568) ? src[3] : 0.f;
        }
        bf16x4 o = {(bf16)v0, (bf16)v1, (bf16)v2, (bf16)v3};
        *(bf16x4*)(ldsA + r * 40 + fs * 4) = o;
      }
    }
#pragma unroll
    for (int it = 0; it < 2; ++it) {
      int p = tid + 256 * it;             // 512 bf16x8 segments (128 rows x 4)
      int n = p >> 2, f = p & 3;
      *(bf16x8*)(ldsB + n * 40 + f * 8) =
          *(const bf16x8*)(Wt + (size_t)(colbase + n) * K + kc + f * 8);
    }
    if (isZ) {
#pragma unroll
      for (int it = 0; it < 2; ++it) {
        int p = tid + 256 * it;
        int n = p >> 2, f = p & 3;
        *(bf16x8*)(ldsB2 + n * 40 + f * 8) =
            *(const bf16x8*)(WtVar + (size_t)(colbase + n) * 576 + kc + f * 8);
      }
    }
    __syncthreads();
    bf16x8 afrag = *(const bf16x8*)(ldsA + (wave * 16 + m) * 40 + quad * 8);
#pragma unroll
    for (int ct = 0; ct < 8; ++ct) {
      bf16x8 bfrag = *(const bf16x8*)(ldsB + (ct * 16 + m) * 40 + quad * 8);
      acc[ct] = __builtin_amdgcn_mfma_f32_16x16x32_bf16(afrag, bfrag, acc[ct], 0, 0, 0);
      if (isZ) {
        bf16x8 b2 = *(const bf16x8*)(ldsB2 + (ct * 16 + m) * 40 + quad * 8);
        accB[ct] = __builtin_amdgcn_mfma_f32_16x16x32_bf16(afrag, b2, accB[ct], 0, 0, 0);
      }
    }
  }
#pragma unroll
  for (int ct = 0; ct < 8; ++ct) {
    const int col = colbase + ct * 16 + m;
    const float bv = bias[col];
#pragma unroll
    for (int r = 0; r < 4; ++r) {
      const size_t row = (size_t)rowbase + wave * 16 + quad * 4 + r;
      float v = acc[ct][r] + bv;
      if (isZ) {
        float lv = accB[ct][r] + b_var[col];
        float zz = eps[row * 256 + col] * __expf(0.5f * lv) + v;
        zout[row * 256 + col] = (bf16)zz;
      } else {
        selfout[row * 256 + col] = (bf16)(v > 0.f ? v : 0.f);
      }
    }
  }
}

// ---------------------------------------------------------------------------
// Fused attention -- ROUND-16: absorbs gemm_qsv and gemm_dualA.
// Per block (4 batches), everything after zself happens here:
//   phase 1   : other_em = relu(agents @ WtOther + b)            (as before)
//   phase 1.5 : MINI-GEMM  K-waves: q = relu(z@Wq+b_q) -> qh16 (bf16)
//                          V-waves: sv = self@Wv2+b_v  -> svl16 (bf16)
//               A-frag rows duplicated mod 4 (lane m -> batch m&3) makes the
//               MFMA output REPLICATED across quads: acc[c][r] = result for
//               batch r at every lane. Bit-identical to the old gemm_qsv
//               (same K order, same bf16 quantization points).
//   main loop : [k | v] unified 80x512 GEMM, ping-pong B        (as before)
//   epilogues : scores -> softmax -> h (into qh16)              (as before)
//   out-GEMM  : out = relu([h; self] @ WA + b_a), 16 chunks (8 h from LDS,
//               8 self from global), replicated rows, quad0 stores f32.
//               Bit-identical to the old gemm_dualA.
// Deletes 2 kernel launches + q/sv/h HBM round-trips. Barriers: 5 (same).
// ---------------------------------------------------------------------------
__global__ __launch_bounds__(512, 4) void k_fused(
    const float* __restrict__ x,
    const bf16* __restrict__ zb, const bf16* __restrict__ selfb,
    const bf16* __restrict__ WtOther, const float* __restrict__ b_other,
    const bf16* __restrict__ WtKc, const float* __restrict__ b_k,
    const bf16* __restrict__ WtVc,
    const bf16* __restrict__ WtQc, const float* __restrict__ b_q,
    const bf16* __restrict__ WtV2c, const float* __restrict__ b_v,
    const bf16* __restrict__ WtA1c, const bf16* __restrict__ WtA2c,
    const float* __restrict__ b_a,
    float* __restrict__ att_out, float* __restrict__ outp)
{
  __shared__ bf16 ldsO[80 * 264];     // 42240 B  other_em (16B-group stride 33)
  __shared__ bf16 ldsA1[80 * 40];     //  6400 B  agents tile; REUSED: spart/attl
  __shared__ bf16 qh16[1024];         //  2048 B  q (bf16); REUSED: h partials
  __shared__ bf16 svl16[1024];        //  2048 B  sv (bf16)
  float* spart = (float*)ldsA1;        // [0..320)  floats: 4 K-waves x 80 rows
  float* attl  = (float*)ldsA1 + 320;  // [320..400) floats: att weights, row order

  const int tid = threadIdx.x, wave = tid >> 6, lane = tid & 63;
  const int quad = lane >> 4, m = lane & 15;
  const int b0 = blockIdx.x * 4;
  const int kvw = wave & 3;            // column-group within K or V half
  const bool isV = wave >= 4;

  // ---- phase 0: stage agents_info (interleaved rows: r = agent*4 + batch)
  for (int i = tid; i < 80 * 16; i += 512) {
    int r = i >> 4, kk = (i & 15) * 2;
    int n = r >> 2, bb = r & 3;
    float v0 = 0.f, v1 = 0.f;
    if (n < 19) {
      const float* base = x + (size_t)(b0 + bb) * NOBS + 36 + n * 28;
      if (kk < 28) v0 = base[kk];
      if (kk + 1 < 28) v1 = base[kk + 1];
    }
    unsigned u0 = bfbits(v0), u1 = bfbits(v1);
    *(unsigned*)(ldsA1 + r * 40 + kk) = u0 | (u1 << 16);
  }

  const f32x4 z4 = {0.f, 0.f, 0.f, 0.f};

  // ---- early issue: main-loop B chunk 0 and mini-GEMM B chunk 0
  const bf16* __restrict__ Bc = isV ? WtVc : WtKc;
  const int cb = (kvw * 64 + m) * 32 + quad * 8;
  bf16x8 bE[4];
#pragma unroll
  for (int c = 0; c < 4; ++c) bE[c] = *(const bf16x8*)(Bc + cb + c * 512);

  const bf16* __restrict__ Wm = isV ? WtV2c : WtQc;       // mini-GEMM B
  const bf16* __restrict__ Am = isV ? selfb : zb;          // mini-GEMM A (global)
  bf16x8 mE[4];
#pragma unroll
  for (int c = 0; c < 4; ++c) mE[c] = *(const bf16x8*)(Wm + cb + c * 512);

  __syncthreads();   // barrier 1: agents tile ready

  // ---- phase 1: other_em = relu(A1 @ WtOther^T + b_other), K=32
  {
    float bo[2];
    bf16x8 bfr[2];
#pragma unroll
    for (int c = 0; c < 2; ++c) {
      int col = (2 * wave + c) * 16 + m;
      bo[c] = b_other[col];
      bfr[c] = *(const bf16x8*)(WtOther + col * 32 + quad * 8);
    }
    f32x4 acc1[5][2];
#pragma unroll
    for (int rt = 0; rt < 5; ++rt) {
      bf16x8 a = *(const bf16x8*)(ldsA1 + (rt * 16 + m) * 40 + quad * 8);
#pragma unroll
      for (int c = 0; c < 2; ++c)
        acc1[rt][c] = __builtin_amdgcn_mfma_f32_16x16x32_bf16(a, bfr[c], z4, 0, 0, 0);
    }
#pragma unroll
    for (int rt = 0; rt < 5; ++rt)
#pragma unroll
      for (int c = 0; c < 2; ++c) {
        int col = (2 * wave + c) * 16 + m;
#pragma unroll
        for (int r = 0; r < 4; ++r) {
          float v = acc1[rt][c][r] + bo[c];
          v = v > 0.f ? v : 0.f;
          unsigned u = bfbits(v);
          unsigned other = (unsigned)__shfl_xor((int)u, 1, 64);
          if ((m & 1) == 0) {
            int rowl = rt * 16 + quad * 4 + r;
            *(unsigned*)(ldsO + rowl * 264 + col) = u | (other << 16);
          }
        }
      }
  }

  // ---- phase 1.5: mini-GEMM (q for K-waves, sv for V-waves), K=256.
  // A rows duplicated mod 4 -> output replicated across quads.
  {
    f32x4 macc[4];
#pragma unroll
    for (int c = 0; c < 4; ++c) macc[c] = z4;
    const bf16* arow = Am + (size_t)(b0 + (m & 3)) * 256 + quad * 8;
#pragma unroll 1
    for (int ch = 0; ch < 8; ch += 2) {
      bf16x8 mO[4];
#pragma unroll
      for (int c = 0; c < 4; ++c)
        mO[c] = *(const bf16x8*)(Wm + (size_t)(ch + 1) * 8192 + cb + c * 512);
      bf16x8 ma0 = *(const bf16x8*)(arow + ch * 32);
#pragma unroll
      for (int c = 0; c < 4; ++c)
        macc[c] = __builtin_amdgcn_mfma_f32_16x16x32_bf16(ma0, mE[c], macc[c], 0, 0, 0);
      // prefetch ch+2; ch==6 reads chunk 8 = adjacent allocated region
#pragma unroll
      for (int c = 0; c < 4; ++c)
        mE[c] = *(const bf16x8*)(Wm + (size_t)(ch + 2) * 8192 + cb + c * 512);
      bf16x8 ma1 = *(const bf16x8*)(arow + (ch + 1) * 32);
#pragma unroll
      for (int c = 0; c < 4; ++c)
        macc[c] = __builtin_amdgcn_mfma_f32_16x16x32_bf16(ma1, mO[c], macc[c], 0, 0, 0);
    }
    const float* bm = isV ? b_v : b_q;
    bf16* dst = isV ? svl16 : qh16;
#pragma unroll
    for (int c = 0; c < 4; ++c) {
      int col = kvw * 64 + c * 16 + m;
      float bv = bm[col];
#pragma unroll
      for (int r = 0; r < 4; ++r) {
        float v = macc[c][r] + bv;
        if (!isV) v = v > 0.f ? v : 0.f;     // relu for q only
        unsigned u = bfbits(v);
        unsigned other = (unsigned)__shfl_xor((int)u, 1, 64);
        if (quad == 0 && (m & 1) == 0)
          *(unsigned*)(dst + r * 256 + col) = u | (other << 16);
      }
    }
  }
  __syncthreads();   // barrier 2: ldsO + qh16 + svl16 ready; ldsA1 -> overlay

  // ---- unified main GEMM: 80 rows x 512 cols ([WtK | WtV]), 8 chunks,
  // ping-pong software pipeline (prefetch distance 1, no conditionals).
  f32x4 acc[5][4];
#pragma unroll
  for (int rt = 0; rt < 5; ++rt)
#pragma unroll
    for (int c = 0; c < 4; ++c) acc[rt][c] = z4;

  {
#pragma unroll 1
    for (int ch = 0; ch < 8; ch += 2) {
      bf16x8 bO[4];
#pragma unroll
      for (int c = 0; c < 4; ++c)
        bO[c] = *(const bf16x8*)(Bc + (size_t)(ch + 1) * 8192 + cb + c * 512);
      const int kc0 = ch * 32;
#pragma unroll
      for (int rt = 0; rt < 5; ++rt) {
        bf16x8 a = *(const bf16x8*)(ldsO + (rt * 16 + m) * 264 + kc0 + quad * 8);
#pragma unroll
        for (int c = 0; c < 4; ++c)
          acc[rt][c] = __builtin_amdgcn_mfma_f32_16x16x32_bf16(a, bE[c], acc[rt][c], 0, 0, 0);
      }
#pragma unroll
      for (int c = 0; c < 4; ++c)
        bE[c] = *(const bf16x8*)(Bc + (size_t)(ch + 2) * 8192 + cb + c * 512);
      const int kc1 = kc0 + 32;
#pragma unroll
      for (int rt = 0; rt < 5; ++rt) {
        bf16x8 a = *(const bf16x8*)(ldsO + (rt * 16 + m) * 264 + kc1 + quad * 8);
#pragma unroll
        for (int c = 0; c < 4; ++c)
          acc[rt][c] = __builtin_amdgcn_mfma_f32_16x16x32_bf16(a, bO[c], acc[rt][c], 0, 0, 0);
      }
    }
  }

  // ---- early issue: out-GEMM B chunk 0 (hides L2 latency under epilogues)
  const int ocb = (wave * 32 + m) * 32 + quad * 8;
  bf16x8 oE[2];
#pragma unroll
  for (int c = 0; c < 2; ++c) oE[c] = *(const bf16x8*)(WtA1c + ocb + c * 512);

  // ---- K-waves: scores = (relu(k)+b_k) . q, reduce over lanes -> spart
  if (!isV) {
    float qreg[4][4], bkreg[4];
#pragma unroll
    for (int c = 0; c < 4; ++c) {
      int col = (4 * wave + c) * 16 + m;
      bkreg[c] = b_k[col];
#pragma unroll
      for (int r = 0; r < 4; ++r) qreg[c][r] = (float)qh16[r * 256 + col];
    }
#pragma unroll
    for (int rt = 0; rt < 5; ++rt) {
      float part[4] = {0.f, 0.f, 0.f, 0.f};
#pragma unroll
      for (int c = 0; c < 4; ++c) {
#pragma unroll
        for (int r = 0; r < 4; ++r) {
          float kv = acc[rt][c][r] + bkreg[c];
          kv = kv > 0.f ? kv : 0.f;
          part[r] += kv * qreg[c][r];
        }
      }
#pragma unroll
      for (int r = 0; r < 4; ++r) {
        float p = part[r];
        p += __shfl_xor(p, 1, 64);
        p += __shfl_xor(p, 2, 64);
        p += __shfl_xor(p, 4, 64);
        p += __shfl_xor(p, 8, 64);
        if (m == 0) spart[wave * 80 + rt * 16 + quad * 4 + r] = p;
      }
    }
  }
  __syncthreads();   // barrier 3: spart ready

  // ---- softmax: wave w = batch w, lanes 0-18 = agents (width-32 tree)
  if (!isV && lane < 32) {
    const int bb = wave, j = lane;
    float s = -1e30f;
    if (j < 19) {
      int row = j * 4 + bb;
      s = (spart[row] + spart[80 + row] + spart[160 + row] + spart[240 + row]) * 0.0625f;
    }
    float mx = s;
#pragma unroll
    for (int off = 16; off >= 1; off >>= 1) mx = fmaxf(mx, __shfl_xor(mx, off, 32));
    float e = (j < 19) ? __expf(s - mx) : 0.f;
    float sum = e;
#pragma unroll
    for (int off = 16; off >= 1; off >>= 1) sum += __shfl_xor(sum, off, 32);
    float inv = 1.f / sum;
    float a = e * inv;
    if (j < 20) attl[j * 4 + bb] = a;
    if (j < 19) att_out[(size_t)(b0 + bb) * 19 + j] = a;
  }
  __syncthreads();   // barrier 4: attl ready

  // ---- V-waves: epilogue  h = sum_rows att * relu(v + sv) -> qh16 (h)
  if (isV) {
    float svreg[4][4];
#pragma unroll
    for (int c = 0; c < 4; ++c) {
      int col = (4 * kvw + c) * 16 + m;
#pragma unroll
      for (int r = 0; r < 4; ++r) svreg[c][r] = (float)svl16[r * 256 + col];
    }
    float hacc[4][4];
#pragma unroll
    for (int c = 0; c < 4; ++c)
#pragma unroll
      for (int r = 0; r < 4; ++r) hacc[c][r] = 0.f;
#pragma unroll
    for (int rt = 0; rt < 5; ++rt) {
      float av[4];
#pragma unroll
      for (int r = 0; r < 4; ++r) av[r] = attl[rt * 16 + quad * 4 + r];
#pragma unroll
      for (int c = 0; c < 4; ++c) {
#pragma unroll
        for (int r = 0; r < 4; ++r) {
          float v = acc[rt][c][r] + svreg[c][r];
          v = v > 0.f ? v : 0.f;
          hacc[c][r] += v * av[r];
        }
      }
    }
#pragma unroll
    for (int c = 0; c < 4; ++c)
#pragma unroll
      for (int r = 0; r < 4; ++r) {
        float h = hacc[c][r];
        h += __shfl_xor(h, 16, 64);
        h += __shfl_xor(h, 32, 64);
        if (quad == 0) qh16[r * 256 + (4 * kvw + c) * 16 + m] = (bf16)h;
      }
  }
  __syncthreads();   // barrier 5: h (in qh16) ready

  // ---- out-GEMM: out = relu([h; self] @ WA + b_a), 16 chunks, 2 ctiles/wave.
  // Chunks 0-7: A = h (qh16, LDS); chunks 8-15: A = self (global).
  // Rows duplicated mod 4 -> output replicated across quads; quad0 stores.
  {
    f32x4 oacc[2];
#pragma unroll
    for (int c = 0; c < 2; ++c) oacc[c] = z4;
    const bf16* srow = selfb + (size_t)(b0 + (m & 3)) * 256 + quad * 8;
#pragma unroll 1
    for (int t = 0; t < 16; t += 2) {
      bf16x8 oO[2];
      const bf16* Wn1 = (t + 1 < 8) ? WtA1c : WtA2c;
#pragma unroll
      for (int c = 0; c < 2; ++c)
        oO[c] = *(const bf16x8*)(Wn1 + (size_t)((t + 1) & 7) * 8192 + ocb + c * 512);
      bf16x8 oa0, oa1;
      if (t < 8) {
        oa0 = *(const bf16x8*)(qh16 + (m & 3) * 256 + t * 32 + quad * 8);
        oa1 = *(const bf16x8*)(qh16 + (m & 3) * 256 + (t + 1) * 32 + quad * 8);
      } else {
        oa0 = *(const bf16x8*)(srow + (t - 8) * 32);
        oa1 = *(const bf16x8*)(srow + (t - 7) * 32);
      }
#pragma unroll
      for (int c = 0; c < 2; ++c)
        oacc[c] = __builtin_amdgcn_mfma_f32_16x16x32_bf16(oa0, oE[c], oacc[c], 0, 0, 0);
      // prefetch t+2; at t==14 this wraps to WtA2 chunk 0 (harmless re-read)
      const bf16* Wn2 = (t + 2 < 8) ? WtA1c : WtA2c;
#pragma unroll
      for (int c = 0; c < 2; ++c)
        oE[c] = *(const bf16x8*)(Wn2 + (size_t)((t + 2) & 7) * 8192 + ocb + c * 512);
#pragma unroll
      for (int c = 0; c < 2; ++c)
        oacc[c] = __builtin_amdgcn_mfma_f32_16x16x32_bf16(oa1, oO[c], oacc[c], 0, 0, 0);
    }
#pragma unroll
    for (int c = 0; c < 2; ++c) {
      const int col = wave * 32 + c * 16 + m;
      const float bv = b_a[col];
#pragma unroll
      for (int r = 0; r < 4; ++r) {
        float v = oacc[c][r] + bv;
        v = v > 0.f ? v : 0.f;
        if (quad == 0) outp[(size_t)(b0 + r) * 256 + col] = v;
      }
    }
  }
}

// ---------------------------------------------------------------------------
extern "C" void kernel_launch(void* const* d_in, const int* in_sizes, int n_in,
                              void* d_out, int out_size, void* d_ws, size_t ws_size,
                              hipStream_t stream) {
  (void)in_sizes; (void)n_in; (void)out_size; (void)ws_size;
  const float* x      = (const float*)d_in[0];
  const float* eps    = (const float*)d_in[1];
  const float* W_mu   = (const float*)d_in[2];
  const float* b_mu   = (const float*)d_in[3];
  const float* W_var  = (const float*)d_in[4];
  const float* b_var  = (const float*)d_in[5];
  const float* W_self = (const float*)d_in[6];
  const float* b_self = (const float*)d_in[7];
  const float* W_other= (const float*)d_in[8];
  const float* b_other= (const float*)d_in[9];
  const float* W_q    = (const float*)d_in[10];
  const float* b_q    = (const float*)d_in[11];
  const float* W_k    = (const float*)d_in[12];
  const float* b_k    = (const float*)d_in[13];
  const float* W_v    = (const float*)d_in[14];
  const float* b_v    = (const float*)d_in[15];
  const float* W_a    = (const float*)d_in[16];
  const float* b_a    = (const float*)d_in[17];

  char* wsb = (char*)d_ws;
  bf16* WtMu    = (bf16*)(wsb + OFF_WT_MU);
  bf16* WtVar   = (bf16*)(wsb + OFF_WT_VAR);
  bf16* WtSelf  = (bf16*)(wsb + OFF_WT_SELF);
  bf16* WtOther = (bf16*)(wsb + OFF_WT_OTHER);
  bf16* WtQ     = (bf16*)(wsb + OFF_WT_Q);
  bf16* WtK     = (bf16*)(wsb + OFF_WT_K);
  bf16* WtV1    = (bf16*)(wsb + OFF_WT_V1);
  bf16* WtV2    = (bf16*)(wsb + OFF_WT_V2);
  bf16* WtA1    = (bf16*)(wsb + OFF_WT_A1);
  bf16* WtA2    = (bf16*)(wsb + OFF_WT_A2);
  bf16* zbuf    = (bf16*)(wsb + OFF_Z);
  bf16* selfbuf = (bf16*)(wsb + OFF_SELF);

  float* out = (float*)d_out;
  float* att_out = out + (size_t)NB * 256;

  dim3 blk(256);
  wprep<<<dim3(160, 10), blk, 0, stream>>>(W_mu, W_var, W_self, W_other, W_q, W_k, W_v, W_a, wsb);
  // z = eps*exp(0.5*logvar)+mu  AND  self_em = relu(x@W_self+b), one launch
  gemm_zself<<<dim3(NB / 64, 4), blk, 0, stream>>>(x, WtMu, WtVar, WtSelf,
                                                   b_mu, b_var, b_self, eps, zbuf, selfbuf);
  // everything else: q/sv mini-GEMMs -> other_em -> [k|v] GEMM -> scores ->
  // softmax -> h -> out-GEMM, all per-block private
  k_fused<<<NB / 4, dim3(512), 0, stream>>>(x, zbuf, selfbuf,
                                            WtOther, b_other, WtK, b_k, WtV1,
                                            WtQ, b_q, WtV2, b_v, WtA1, WtA2, b_a,
                                            att_out, out);
}

// Round 7
// 354.617 us; speedup vs baseline: 1.3596x; 1.3596x over previous
//
#include <hip/hip_runtime.h>

typedef __bf16 bf16;
typedef __bf16 bf16x4 __attribute__((ext_vector_type(4)));
typedef __bf16 bf16x8 __attribute__((ext_vector_type(8)));
typedef float  f32x4  __attribute__((ext_vector_type(4)));

// Problem constants
#define NB    16384      // batch
#define NOBS  568
#define NH    256
#define NAG   19         // N_OTHER

// ws byte offsets (all 16B aligned)
#define OFF_WT_MU    0u          // FLAT [256][576] bf16
#define OFF_WT_VAR   294912u     // FLAT [256][576]
#define OFF_WT_SELF  589824u     // FLAT [256][64]
#define OFF_WT_OTHER 622592u     // [256][32]  (chunk-major == flat at K=32)
#define OFF_WT_Q     638976u     // CHUNK-MAJOR [8][256][32] (chunk-8 overflow -> WT_K)
#define OFF_WT_K     770048u     // CHUNK-MAJOR [8][256][32] (chunk-8 overflow -> V1)
#define OFF_WT_V1    901120u     // CHUNK-MAJOR [8][256][32] (chunk-8 overflow -> V2)
#define OFF_WT_V2    1032192u    // CHUNK-MAJOR [8][256][32] (chunk-8 overflow -> A1)
#define OFF_WT_A1    1163264u    // CHUNK-MAJOR [8][256][32]
#define OFF_WT_A2    1294336u    // CHUNK-MAJOR [8][256][32]
#define OFF_Z        1425408u    // UNUSED since round 17 (z lives in LDS only)
#define OFF_SELF     9814016u
#define OFF_Q        18202624u
#define OFF_SV       26591232u
#define OFF_H        34979840u

static __device__ __forceinline__ unsigned short bfbits(float v) {
  bf16 b = (bf16)v;
  union { bf16 b; unsigned short u; } cvt; cvt.b = b; return cvt.u;
}

// async global->LDS, 16B per lane; dest = wave-uniform base + lane*16
static __device__ __forceinline__ void gload16(const bf16* g, bf16* l) {
  __builtin_amdgcn_global_load_lds(
      (const __attribute__((address_space(1))) void*)g,
      (__attribute__((address_space(3))) void*)(void*)l, 16, 0, 0);
}

// ---------------------------------------------------------------------------
// Weight prep (round-15 version, unchanged).
// ---------------------------------------------------------------------------
__global__ __launch_bounds__(256) void wprep(
    const float* __restrict__ Wmu, const float* __restrict__ Wvar,
    const float* __restrict__ Wself, const float* __restrict__ Wother,
    const float* __restrict__ Wq, const float* __restrict__ Wk,
    const float* __restrict__ Wv, const float* __restrict__ Wa, char* wsb)
{
  const float* src; bf16* dst; int K, Kp; bool chunked = false;
  switch (blockIdx.y) {
    case 0: src = Wmu;        dst = (bf16*)(wsb + OFF_WT_MU);    K = 568; Kp = 576; break;
    case 1: src = Wvar;       dst = (bf16*)(wsb + OFF_WT_VAR);   K = 568; Kp = 576; break;
    case 2: src = Wself;      dst = (bf16*)(wsb + OFF_WT_SELF);  K = 36;  Kp = 64;  break;
    case 3: src = Wother;     dst = (bf16*)(wsb + OFF_WT_OTHER); K = 28;  Kp = 32;  break;
    case 4: src = Wq;         dst = (bf16*)(wsb + OFF_WT_Q);     K = 256; Kp = 256; chunked = true; break;
    case 5: src = Wk;         dst = (bf16*)(wsb + OFF_WT_K);     K = 256; Kp = 256; chunked = true; break;
    case 6: src = Wv;         dst = (bf16*)(wsb + OFF_WT_V1);    K = 256; Kp = 256; chunked = true; break;
    case 7: src = Wv + 65536; dst = (bf16*)(wsb + OFF_WT_V2);    K = 256; Kp = 256; chunked = true; break;
    case 8: src = Wa;         dst = (bf16*)(wsb + OFF_WT_A1);    K = 256; Kp = 256; chunked = true; break;
    default: src = Wa + 65536; dst = (bf16*)(wsb + OFF_WT_A2);   K = 256; Kp = 256; chunked = true; break;
  }
  int total = 256 * Kp;
  if (chunked) {
    for (int i = blockIdx.x * 256 + threadIdx.x; i < total; i += gridDim.x * 256) {
      int ch = i >> 13, n = (i >> 5) & 255, kk = i & 31;
      int k = ch * 32 + kk;
      dst[i] = (bf16)src[k * 256 + n];
    }
  } else {
    for (int i = blockIdx.x * 256 + threadIdx.x; i < total; i += gridDim.x * 256) {
      int n = i / Kp, k = i - n * Kp;
      dst[i] = (k < K) ? (bf16)src[k * 256 + n] : (bf16)0.f;
    }
  }
}

// ---------------------------------------------------------------------------
// ROUND-17: merged zself + qsv at 64-rows-per-block amortization.
// grid (256, 2): y=0 -> z (K=576, dual-B, full 256 cols) then q = relu(z@Wq);
//                y=1 -> self (K=64) then sv = self@Wv2.
// Phase A: byte-identical zself math, widened to 256 cols (acc 32 x f32x4,
//   B panels LDS-staged per BK=32 exactly as the proven zself).
// z -> LDS ONLY (overlaid on the dead B-panel LDS; no HBM round-trip).
// Phase B: q/sv from LDS-z; B streamed per-wave from chunk-major global with
//   the k_fused-proven ping-pong (4 ctiles/wave, prefetch distance 1, tail
//   over-prefetch into the adjacent allocated weight region).
// Same K-chunk order as the old kernels everywhere -> bit-identical outputs.
// LDS 46 KB. Lesson from round 6: only fuse GEMMs when the block's rows
// (64 here) amortize the weight-panel traffic -- 4-batch blocks cannot.
// ---------------------------------------------------------------------------
__global__ __launch_bounds__(256, 2) void gemm_zq(
    const float* __restrict__ x,
    const bf16* __restrict__ WtMu, const bf16* __restrict__ WtVar,
    const bf16* __restrict__ WtSelf,
    const bf16* __restrict__ WtQc, const bf16* __restrict__ WtV2c,
    const float* __restrict__ b_mu, const float* __restrict__ b_var,
    const float* __restrict__ b_self,
    const float* __restrict__ b_q, const float* __restrict__ b_v,
    const float* __restrict__ eps,
    bf16* __restrict__ qout, bf16* __restrict__ selfout, bf16* __restrict__ svout)
{
  __shared__ bf16 ldsA[64 * 40];        //  5120 B
  __shared__ bf16 ldsBU[2 * 256 * 40];  // 40960 B: Bmu|Bvar in phase A; z (64x264
                                        //          = 33792 B) afterwards
  bf16* ldsB  = ldsBU;
  bf16* ldsB2 = ldsBU + 256 * 40;
  bf16* zl    = ldsBU;                  // overlay, valid after phase A barrier

  const int tid = threadIdx.x;
  const int wave = tid >> 6;
  const int lane = tid & 63;
  const int quad = lane >> 4;
  const int m = lane & 15;
  const int rowbase = blockIdx.x * 64;
  const bool isZ = blockIdx.y == 0;
  const int KA = isZ ? 576 : 64;
  const bf16* __restrict__ W1 = isZ ? WtMu : WtSelf;

  const f32x4 z4 = {0.f, 0.f, 0.f, 0.f};
  f32x4 a1[16], a2[16];
#pragma unroll
  for (int ct = 0; ct < 16; ++ct) { a1[ct] = z4; a2[ct] = z4; }

  // ---- phase A: full-width (256-col) GEMM, LDS-staged A and B per BK=32
  for (int kc = 0; kc < KA; kc += 32) {
    __syncthreads();
    {
#pragma unroll
      for (int it = 0; it < 2; ++it) {
        int p = tid + 256 * it;          // 512 float4 segments (64 rows x 8)
        int r = p >> 3, fs = p & 7;
        int k = kc + fs * 4;
        const float* src = x + (size_t)(rowbase + r) * 568 + k;
        float v0, v1, v2, v3;
        if (k + 4 <= 568) {
          float4 v = *(const float4*)src;
          v0 = v.x; v1 = v.y; v2 = v.z; v3 = v.w;
        } else {
          v0 = (k + 0 < 568) ? src[0] : 0.f;
          v1 = (k + 1 < 568) ? src[1] : 0.f;
          v2 = (k + 2 < 568) ? src[2] : 0.f;
          v3 = (k + 3 < 568) ? src[3] : 0.f;
        }
        bf16x4 o = {(bf16)v0, (bf16)v1, (bf16)v2, (bf16)v3};
        *(bf16x4*)(ldsA + r * 40 + fs * 4) = o;
      }
    }
#pragma unroll
    for (int it = 0; it < 4; ++it) {
      int p = tid + 256 * it;             // 1024 bf16x8 segments (256 rows x 4)
      int n = p >> 2, f = p & 3;
      *(bf16x8*)(ldsB + n * 40 + f * 8) =
          *(const bf16x8*)(W1 + (size_t)n * KA + kc + f * 8);
    }
    if (isZ) {
#pragma unroll
      for (int it = 0; it < 4; ++it) {
        int p = tid + 256 * it;
        int n = p >> 2, f = p & 3;
        *(bf16x8*)(ldsB2 + n * 40 + f * 8) =
            *(const bf16x8*)(WtVar + (size_t)n * 576 + kc + f * 8);
      }
    }
    __syncthreads();
    bf16x8 afrag = *(const bf16x8*)(ldsA + (wave * 16 + m) * 40 + quad * 8);
#pragma unroll
    for (int ct = 0; ct < 16; ++ct) {
      bf16x8 bfrag = *(const bf16x8*)(ldsB + (ct * 16 + m) * 40 + quad * 8);
      a1[ct] = __builtin_amdgcn_mfma_f32_16x16x32_bf16(afrag, bfrag, a1[ct], 0, 0, 0);
      if (isZ) {
        bf16x8 b2 = *(const bf16x8*)(ldsB2 + (ct * 16 + m) * 40 + quad * 8);
        a2[ct] = __builtin_amdgcn_mfma_f32_16x16x32_bf16(afrag, b2, a2[ct], 0, 0, 0);
      }
    }
  }
  __syncthreads();   // all B-panel reads done; ldsBU may be overwritten as zl

  // ---- phase A epilogue: z (or self) -> bf16 -> zl; self also -> global
#pragma unroll
  for (int ct = 0; ct < 16; ++ct) {
    const int col = ct * 16 + m;
    const float bv1 = isZ ? b_mu[col] : b_self[col];
    const float bv2 = isZ ? b_var[col] : 0.f;
#pragma unroll
    for (int r = 0; r < 4; ++r) {
      const int rowl = wave * 16 + quad * 4 + r;
      const size_t row = (size_t)rowbase + rowl;
      float v;
      if (isZ) {
        float mu = a1[ct][r] + bv1;
        float lv = a2[ct][r] + bv2;
        v = eps[row * 256 + col] * __expf(0.5f * lv) + mu;
      } else {
        v = a1[ct][r] + bv1;
        v = v > 0.f ? v : 0.f;
      }
      unsigned u = bfbits(v);
      unsigned other = (unsigned)__shfl_xor((int)u, 1, 64);
      if ((m & 1) == 0) {
        unsigned pk = u | (other << 16);
        *(unsigned*)(zl + rowl * 264 + col) = pk;
        if (!isZ) *(unsigned*)(selfout + row * 256 + col) = pk;
      }
    }
  }
  __syncthreads();   // zl fully written before cross-wave reads

  // ---- phase B: q = relu(zl@Wq+b_q) or sv = zl@Wv2+b_v; K=256 ping-pong.
  // Wave owns 64 cols (4 ctiles) x 64 rows (4 rtiles).
  {
    const bf16* __restrict__ W3 = isZ ? WtQc : WtV2c;
    const int cb = (wave * 64 + m) * 32 + quad * 8;   // + c*512 per ctile
    f32x4 oacc[4][4];
#pragma unroll
    for (int rt = 0; rt < 4; ++rt)
#pragma unroll
      for (int c = 0; c < 4; ++c) oacc[rt][c] = z4;
    bf16x8 pE[4];
#pragma unroll
    for (int c = 0; c < 4; ++c) pE[c] = *(const bf16x8*)(W3 + cb + c * 512);
#pragma unroll 1
    for (int ch = 0; ch < 8; ch += 2) {
      bf16x8 pO[4];
#pragma unroll
      for (int c = 0; c < 4; ++c)
        pO[c] = *(const bf16x8*)(W3 + (size_t)(ch + 1) * 8192 + cb + c * 512);
#pragma unroll
      for (int rt = 0; rt < 4; ++rt) {
        bf16x8 a = *(const bf16x8*)(zl + (rt * 16 + m) * 264 + ch * 32 + quad * 8);
#pragma unroll
        for (int c = 0; c < 4; ++c)
          oacc[rt][c] = __builtin_amdgcn_mfma_f32_16x16x32_bf16(a, pE[c], oacc[rt][c], 0, 0, 0);
      }
      // prefetch ch+2; ch==6 reads chunk 8 = adjacent allocated weight region
#pragma unroll
      for (int c = 0; c < 4; ++c)
        pE[c] = *(const bf16x8*)(W3 + (size_t)(ch + 2) * 8192 + cb + c * 512);
#pragma unroll
      for (int rt = 0; rt < 4; ++rt) {
        bf16x8 a = *(const bf16x8*)(zl + (rt * 16 + m) * 264 + (ch + 1) * 32 + quad * 8);
#pragma unroll
        for (int c = 0; c < 4; ++c)
          oacc[rt][c] = __builtin_amdgcn_mfma_f32_16x16x32_bf16(a, pO[c], oacc[rt][c], 0, 0, 0);
      }
    }
    const float* __restrict__ b3 = isZ ? b_q : b_v;
    bf16* __restrict__ out3 = isZ ? qout : svout;
#pragma unroll
    for (int rt = 0; rt < 4; ++rt)
#pragma unroll
      for (int c = 0; c < 4; ++c) {
        const int col = wave * 64 + c * 16 + m;
        const float bv = b3[col];
#pragma unroll
        for (int r = 0; r < 4; ++r) {
          const size_t row = (size_t)rowbase + rt * 16 + quad * 4 + r;
          float v = oacc[rt][c][r] + bv;
          if (isZ) v = v > 0.f ? v : 0.f;
          unsigned u = bfbits(v);
          unsigned other = (unsigned)__shfl_xor((int)u, 1, 64);
          if ((m & 1) == 0)
            *(unsigned*)(out3 + row * 256 + col) = u | (other << 16);
        }
      }
  }
}

// ---------------------------------------------------------------------------
// dual-A GEMM (round-15 async version, unchanged).
// ---------------------------------------------------------------------------
__global__ __launch_bounds__(256, 4) void gemm_dualA(
    const bf16* __restrict__ A1, const bf16* __restrict__ A2,
    const bf16* __restrict__ Wt1c, const bf16* __restrict__ Wt2c,
    const float* __restrict__ bias, float* __restrict__ outp)
{
  __shared__ __align__(16) bf16 lA[2][64 * 32];
  __shared__ __align__(16) bf16 lB[2][128 * 32];

  const int tid = threadIdx.x;
  const int wave = tid >> 6;
  const int lane = tid & 63;
  const int quad = lane >> 4;
  const int m = lane & 15;
  const int rowbase = blockIdx.x * 64;
  const int colbase = blockIdx.y * 128;

  f32x4 acc[8];
  const f32x4 z4 = {0.f, 0.f, 0.f, 0.f};
#pragma unroll
  for (int ct = 0; ct < 8; ++ct) acc[ct] = z4;

  const size_t arow = (size_t)(rowbase + (tid >> 2)) * 256 + (tid & 3) * 8;
  const size_t bbase = (size_t)colbase * 32 + (size_t)tid * 8;

  auto stageT = [&](int buf, int t) {
    const int ch = t & 7;
    const bf16* Astep = (t < 8) ? A1 : A2;
    const bf16* Wstep = (t < 8) ? Wt1c : Wt2c;
    const size_t cof = (size_t)ch * 8192;
    gload16(Astep + arow + ch * 32, &lA[buf][wave * 512]);
    gload16(Wstep + cof + bbase, &lB[buf][wave * 512]);
    gload16(Wstep + cof + bbase + 2048, &lB[buf][2048 + wave * 512]);
  };

  stageT(0, 0);
  __syncthreads();

#pragma unroll
  for (int t = 0; t < 16; ++t) {
    const int cur = t & 1;
    if (t < 15) stageT(cur ^ 1, t + 1);
    bf16x8 afrag = *(const bf16x8*)(&lA[cur][(wave * 16 + m) * 32 + quad * 8]);
#pragma unroll
    for (int ct = 0; ct < 8; ++ct) {
      bf16x8 bfrag = *(const bf16x8*)(&lB[cur][(ct * 16 + m) * 32 + quad * 8]);
      acc[ct] = __builtin_amdgcn_mfma_f32_16x16x32_bf16(afrag, bfrag, acc[ct], 0, 0, 0);
    }
    __syncthreads();
  }

#pragma unroll
  for (int ct = 0; ct < 8; ++ct) {
    const int col = colbase + ct * 16 + m;
    const float bv = bias[col];
#pragma unroll
    for (int r = 0; r < 4; ++r) {
      const size_t row = (size_t)rowbase + wave * 16 + quad * 4 + r;
      float v = acc[ct][r] + bv;
      outp[row * 256 + col] = (v > 0.f ? v : 0.f);
    }
  }
}

// ---------------------------------------------------------------------------
// Fused attention (round-3/5 version, best measured 158 us; unchanged).
// ---------------------------------------------------------------------------
__global__ __launch_bounds__(512, 4) void k_fused(
    const float* __restrict__ x, const bf16* __restrict__ qb,
    const bf16* __restrict__ svb,
    const bf16* __restrict__ WtOther, const float* __restrict__ b_other,
    const bf16* __restrict__ WtKc, const float* __restrict__ b_k,
    const bf16* __restrict__ WtVc,
    float* __restrict__ att_out, bf16* __restrict__ hb)
{
  __shared__ bf16 ldsO[80 * 264];     // 42240 B  other_em (16B-group stride 33)
  __shared__ bf16 ldsA1[80 * 40];     //  6400 B  agents tile; REUSED: spart/attl
  __shared__ bf16 qh16[1024];         //  2048 B  q (bf16); REUSED: h partials
  __shared__ bf16 svl16[1024];        //  2048 B  sv (bf16)
  float* spart = (float*)ldsA1;        // [0..320)  floats: 4 K-waves x 80 rows
  float* attl  = (float*)ldsA1 + 320;  // [320..400) floats: att weights, row order

  const int tid = threadIdx.x, wave = tid >> 6, lane = tid & 63;
  const int quad = lane >> 4, m = lane & 15;
  const int b0 = blockIdx.x * 4;
  const int kvw = wave & 3;            // column-group within K or V half
  const bool isV = wave >= 4;

  // ---- phase 0: stage q, sv (bf16 copies), agents_info (interleaved rows)
  ((unsigned*)qh16)[tid]  = ((const unsigned*)(qb  + (size_t)b0 * 256))[tid];
  ((unsigned*)svl16)[tid] = ((const unsigned*)(svb + (size_t)b0 * 256))[tid];
  for (int i = tid; i < 80 * 16; i += 512) {
    int r = i >> 4, kk = (i & 15) * 2;   // lds row r = agent*4 + batch
    int n = r >> 2, bb = r & 3;
    float v0 = 0.f, v1 = 0.f;
    if (n < 19) {
      const float* base = x + (size_t)(b0 + bb) * NOBS + 36 + n * 28;
      if (kk < 28) v0 = base[kk];
      if (kk + 1 < 28) v1 = base[kk + 1];
    }
    unsigned u0 = bfbits(v0), u1 = bfbits(v1);
    *(unsigned*)(ldsA1 + r * 40 + kk) = u0 | (u1 << 16);
  }

  const f32x4 z4 = {0.f, 0.f, 0.f, 0.f};

  // ---- issue first main-loop B buffer early (independent of all LDS)
  const bf16* __restrict__ Bc = isV ? WtVc : WtKc;
  const int cb = (kvw * 64 + m) * 32 + quad * 8;   // ((4*kvw+c)*16+m)*32+q*8 == cb+c*512
  bf16x8 bE[4];
#pragma unroll
  for (int c = 0; c < 4; ++c) bE[c] = *(const bf16x8*)(Bc + cb + c * 512);

  __syncthreads();

  // ---- phase 1: other_em = relu(A1 @ WtOther^T + b_other), K=32.
  {
    float bo[2];
    bf16x8 bfr[2];
#pragma unroll
    for (int c = 0; c < 2; ++c) {
      int col = (2 * wave + c) * 16 + m;
      bo[c] = b_other[col];
      bfr[c] = *(const bf16x8*)(WtOther + col * 32 + quad * 8);
    }
    f32x4 acc1[5][2];
#pragma unroll
    for (int rt = 0; rt < 5; ++rt) {
      bf16x8 a = *(const bf16x8*)(ldsA1 + (rt * 16 + m) * 40 + quad * 8);
#pragma unroll
      for (int c = 0; c < 2; ++c)
        acc1[rt][c] = __builtin_amdgcn_mfma_f32_16x16x32_bf16(a, bfr[c], z4, 0, 0, 0);
    }
#pragma unroll
    for (int rt = 0; rt < 5; ++rt)
#pragma unroll
      for (int c = 0; c < 2; ++c) {
        int col = (2 * wave + c) * 16 + m;
#pragma unroll
        for (int r = 0; r < 4; ++r) {
          float v = acc1[rt][c][r] + bo[c];
          v = v > 0.f ? v : 0.f;
          unsigned u = bfbits(v);
          unsigned other = (unsigned)__shfl_xor((int)u, 1, 64);
          if ((m & 1) == 0) {
            int rowl = rt * 16 + quad * 4 + r;
            *(unsigned*)(ldsO + rowl * 264 + col) = u | (other << 16);
          }
        }
      }
  }
  __syncthreads();   // ldsA1 (agents tile) dead from here; spart/attl overlay

  // ---- unified main GEMM: 80 rows x 512 cols ([WtK | WtV]), 8 chunks,
  // ping-pong software pipeline (prefetch distance 1, no conditionals).
  f32x4 acc[5][4];
#pragma unroll
  for (int rt = 0; rt < 5; ++rt)
#pragma unroll
    for (int c = 0; c < 4; ++c) acc[rt][c] = z4;

  {
#pragma unroll 1
    for (int ch = 0; ch < 8; ch += 2) {
      bf16x8 bO[4];
#pragma unroll
      for (int c = 0; c < 4; ++c)
        bO[c] = *(const bf16x8*)(Bc + (size_t)(ch + 1) * 8192 + cb + c * 512);
      const int kc0 = ch * 32;
#pragma unroll
      for (int rt = 0; rt < 5; ++rt) {
        bf16x8 a = *(const bf16x8*)(ldsO + (rt * 16 + m) * 264 + kc0 + quad * 8);
#pragma unroll
        for (int c = 0; c < 4; ++c)
          acc[rt][c] = __builtin_amdgcn_mfma_f32_16x16x32_bf16(a, bE[c], acc[rt][c], 0, 0, 0);
      }
      // prefetch ch+2; at ch==6 this reads chunk 8 = adjacent weight region
#pragma unroll
      for (int c = 0; c < 4; ++c)
        bE[c] = *(const bf16x8*)(Bc + (size_t)(ch + 2) * 8192 + cb + c * 512);
      const int kc1 = kc0 + 32;
#pragma unroll
      for (int rt = 0; rt < 5; ++rt) {
        bf16x8 a = *(const bf16x8*)(ldsO + (rt * 16 + m) * 264 + kc1 + quad * 8);
#pragma unroll
        for (int c = 0; c < 4; ++c)
          acc[rt][c] = __builtin_amdgcn_mfma_f32_16x16x32_bf16(a, bO[c], acc[rt][c], 0, 0, 0);
      }
    }
  }

  // ---- K-waves: scores = (relu(k)+b_k) . q, reduce over lanes -> spart
  if (!isV) {
    float qreg[4][4], bkreg[4];
#pragma unroll
    for (int c = 0; c < 4; ++c) {
      int col = (4 * wave + c) * 16 + m;
      bkreg[c] = b_k[col];
#pragma unroll
      for (int r = 0; r < 4; ++r) qreg[c][r] = (float)qh16[r * 256 + col];
    }
#pragma unroll
    for (int rt = 0; rt < 5; ++rt) {
      float part[4] = {0.f, 0.f, 0.f, 0.f};
#pragma unroll
      for (int c = 0; c < 4; ++c) {
#pragma unroll
        for (int r = 0; r < 4; ++r) {
          float kv = acc[rt][c][r] + bkreg[c];
          kv = kv > 0.f ? kv : 0.f;
          part[r] += kv * qreg[c][r];
        }
      }
#pragma unroll
      for (int r = 0; r < 4; ++r) {
        float p = part[r];
        p += __shfl_xor(p, 1, 64);
        p += __shfl_xor(p, 2, 64);
        p += __shfl_xor(p, 4, 64);
        p += __shfl_xor(p, 8, 64);
        if (m == 0) spart[wave * 80 + rt * 16 + quad * 4 + r] = p;
      }
    }
  }
  __syncthreads();

  // ---- softmax: wave w = batch w, lanes 0-18 = agents (width-32 tree)
  if (!isV && lane < 32) {
    const int bb = wave, j = lane;      // batch, agent
    float s = -1e30f;
    if (j < 19) {
      int row = j * 4 + bb;             // interleaved: row = agent*4 + batch
      s = (spart[row] + spart[80 + row] + spart[160 + row] + spart[240 + row]) * 0.0625f;
    }
    float mx = s;
#pragma unroll
    for (int off = 16; off >= 1; off >>= 1) mx = fmaxf(mx, __shfl_xor(mx, off, 32));
    float e = (j < 19) ? __expf(s - mx) : 0.f;
    float sum = e;
#pragma unroll
    for (int off = 16; off >= 1; off >>= 1) sum += __shfl_xor(sum, off, 32);
    float inv = 1.f / sum;
    float a = e * inv;
    if (j < 20) attl[j * 4 + bb] = a;   // j==19 writes the zero pad row
    if (j < 19) att_out[(size_t)(b0 + bb) * 19 + j] = a;
  }
  __syncthreads();

  // ---- V-waves: epilogue  h = sum_rows att * relu(v + sv)
  if (isV) {
    float svreg[4][4];
#pragma unroll
    for (int c = 0; c < 4; ++c) {
      int col = (4 * kvw + c) * 16 + m;
#pragma unroll
      for (int r = 0; r < 4; ++r) svreg[c][r] = (float)svl16[r * 256 + col];
    }
    float hacc[4][4];   // [c][batch==r]
#pragma unroll
    for (int c = 0; c < 4; ++c)
#pragma unroll
      for (int r = 0; r < 4; ++r) hacc[c][r] = 0.f;
#pragma unroll
    for (int rt = 0; rt < 5; ++rt) {
      float av[4];
#pragma unroll
      for (int r = 0; r < 4; ++r) av[r] = attl[rt * 16 + quad * 4 + r];
#pragma unroll
      for (int c = 0; c < 4; ++c) {
#pragma unroll
        for (int r = 0; r < 4; ++r) {
          float v = acc[rt][c][r] + svreg[c][r];
          v = v > 0.f ? v : 0.f;
          hacc[c][r] += v * av[r];
        }
      }
    }
#pragma unroll
    for (int c = 0; c < 4; ++c)
#pragma unroll
      for (int r = 0; r < 4; ++r) {
        float h = hacc[c][r];
        h += __shfl_xor(h, 16, 64);
        h += __shfl_xor(h, 32, 64);
        if (quad == 0) qh16[r * 256 + (4 * kvw + c) * 16 + m] = (bf16)h;
      }
  }
  __syncthreads();
  ((unsigned*)(hb + (size_t)b0 * 256))[tid] = ((const unsigned*)qh16)[tid];
}

// ---------------------------------------------------------------------------
extern "C" void kernel_launch(void* const* d_in, const int* in_sizes, int n_in,
                              void* d_out, int out_size, void* d_ws, size_t ws_size,
                              hipStream_t stream) {
  (void)in_sizes; (void)n_in; (void)out_size; (void)ws_size;
  const float* x      = (const float*)d_in[0];
  const float* eps    = (const float*)d_in[1];
  const float* W_mu   = (const float*)d_in[2];
  const float* b_mu   = (const float*)d_in[3];
  const float* W_var  = (const float*)d_in[4];
  const float* b_var  = (const float*)d_in[5];
  const float* W_self = (const float*)d_in[6];
  const float* b_self = (const float*)d_in[7];
  const float* W_other= (const float*)d_in[8];
  const float* b_other= (const float*)d_in[9];
  const float* W_q    = (const float*)d_in[10];
  const float* b_q    = (const float*)d_in[11];
  const float* W_k    = (const float*)d_in[12];
  const float* b_k    = (const float*)d_in[13];
  const float* W_v    = (const float*)d_in[14];
  const float* b_v    = (const float*)d_in[15];
  const float* W_a    = (const float*)d_in[16];
  const float* b_a    = (const float*)d_in[17];

  char* wsb = (char*)d_ws;
  bf16* WtMu    = (bf16*)(wsb + OFF_WT_MU);
  bf16* WtVar   = (bf16*)(wsb + OFF_WT_VAR);
  bf16* WtSelf  = (bf16*)(wsb + OFF_WT_SELF);
  bf16* WtOther = (bf16*)(wsb + OFF_WT_OTHER);
  bf16* WtQ     = (bf16*)(wsb + OFF_WT_Q);
  bf16* WtK     = (bf16*)(wsb + OFF_WT_K);
  bf16* WtV1    = (bf16*)(wsb + OFF_WT_V1);
  bf16* WtV2    = (bf16*)(wsb + OFF_WT_V2);
  bf16* WtA1    = (bf16*)(wsb + OFF_WT_A1);
  bf16* WtA2    = (bf16*)(wsb + OFF_WT_A2);
  bf16* selfbuf = (bf16*)(wsb + OFF_SELF);
  bf16* qbuf    = (bf16*)(wsb + OFF_Q);
  bf16* svbuf   = (bf16*)(wsb + OFF_SV);
  bf16* hbuf    = (bf16*)(wsb + OFF_H);

  float* out = (float*)d_out;
  float* att_out = out + (size_t)NB * 256;

  dim3 blk(256);
  wprep<<<dim3(160, 10), blk, 0, stream>>>(W_mu, W_var, W_self, W_other, W_q, W_k, W_v, W_a, wsb);
  // merged front-end: y=0 z->q, y=1 self->sv (z never touches HBM)
  gemm_zq<<<dim3(NB / 64, 2), blk, 0, stream>>>(x, WtMu, WtVar, WtSelf, WtQ, WtV2,
                                                b_mu, b_var, b_self, b_q, b_v, eps,
                                                qbuf, selfbuf, svbuf);
  // fused: other_em -> [k | v] unified GEMM -> scores -> softmax -> h
  k_fused<<<NB / 4, dim3(512), 0, stream>>>(x, qbuf, svbuf, WtOther, b_other, WtK, b_k,
                                            WtV1, att_out, hbuf);
  // out = relu([h; self_em] @ W_a + b_a)   (dual-A, async staged)
  gemm_dualA<<<dim3(NB / 64, 2), blk, 0, stream>>>(hbuf, selfbuf, WtA1, WtA2, b_a, out);
}

// Round 8
// 328.022 us; speedup vs baseline: 1.4699x; 1.0811x over previous
//
#include <hip/hip_runtime.h>

typedef __bf16 bf16;
typedef __bf16 bf16x4 __attribute__((ext_vector_type(4)));
typedef __bf16 bf16x8 __attribute__((ext_vector_type(8)));
typedef float  f32x4  __attribute__((ext_vector_type(4)));

// Problem constants
#define NB    16384      // batch
#define NOBS  568
#define NH    256
#define NAG   19         // N_OTHER

// ws byte offsets (all 16B aligned). ALL weights CHUNK-MAJOR [K/32][256][32].
#define OFF_WT_MU    0u          // [18][256][32]
#define OFF_WT_VAR   294912u     // [18][256][32]
#define OFF_WT_SELF  589824u     // [2][256][32]
#define OFF_WT_OTHER 622592u     // [1][256][32]
#define OFF_WT_Q     638976u     // [8][256][32] (chunk-8 overflow -> WT_K)
#define OFF_WT_K     770048u     // [8][256][32] (chunk-8 overflow -> V1)
#define OFF_WT_V1    901120u     // [8][256][32] (chunk-8 overflow -> V2)
#define OFF_WT_V2    1032192u    // [8][256][32] (chunk-8 overflow -> A1)
#define OFF_WT_A1    1163264u    // [8][256][32]
#define OFF_WT_A2    1294336u    // [8][256][32]
#define OFF_Z        1425408u    // [16384][256] bf16
#define OFF_SELF     9814016u
#define OFF_Q        18202624u
#define OFF_SV       26591232u
#define OFF_H        34979840u

static __device__ __forceinline__ unsigned short bfbits(float v) {
  bf16 b = (bf16)v;
  union { bf16 b; unsigned short u; } cvt; cvt.b = b; return cvt.u;
}

// async global->LDS, 16B per lane; dest = wave-uniform base + lane*16
static __device__ __forceinline__ void gload16(const bf16* g, bf16* l) {
  __builtin_amdgcn_global_load_lds(
      (const __attribute__((address_space(1))) void*)g,
      (__attribute__((address_space(3))) void*)(void*)l, 16, 0, 0);
}

// ---------------------------------------------------------------------------
// Weight prep. ROUND-18: (a) all dsts chunk-major [K/32][256][32], zero-pad
// past K; (b) COALESCED READS -- n is the inner thread index, so src reads
// src[k*256+n] are stride-1 across lanes (the latency-chained side); the
// scattered 2B writes are fire-and-forget into L2.
// ---------------------------------------------------------------------------
__global__ __launch_bounds__(256) void wprep(
    const float* __restrict__ Wmu, const float* __restrict__ Wvar,
    const float* __restrict__ Wself, const float* __restrict__ Wother,
    const float* __restrict__ Wq, const float* __restrict__ Wk,
    const float* __restrict__ Wv, const float* __restrict__ Wa, char* wsb)
{
  const float* src; bf16* dst; int K, Kp;
  switch (blockIdx.y) {
    case 0: src = Wmu;        dst = (bf16*)(wsb + OFF_WT_MU);    K = 568; Kp = 576; break;
    case 1: src = Wvar;       dst = (bf16*)(wsb + OFF_WT_VAR);   K = 568; Kp = 576; break;
    case 2: src = Wself;      dst = (bf16*)(wsb + OFF_WT_SELF);  K = 36;  Kp = 64;  break;
    case 3: src = Wother;     dst = (bf16*)(wsb + OFF_WT_OTHER); K = 28;  Kp = 32;  break;
    case 4: src = Wq;         dst = (bf16*)(wsb + OFF_WT_Q);     K = 256; Kp = 256; break;
    case 5: src = Wk;         dst = (bf16*)(wsb + OFF_WT_K);     K = 256; Kp = 256; break;
    case 6: src = Wv;         dst = (bf16*)(wsb + OFF_WT_V1);    K = 256; Kp = 256; break;
    case 7: src = Wv + 65536; dst = (bf16*)(wsb + OFF_WT_V2);    K = 256; Kp = 256; break;
    case 8: src = Wa;         dst = (bf16*)(wsb + OFF_WT_A1);    K = 256; Kp = 256; break;
    default: src = Wa + 65536; dst = (bf16*)(wsb + OFF_WT_A2);   K = 256; Kp = 256; break;
  }
  int total = 256 * Kp;
  for (int i = blockIdx.x * 256 + threadIdx.x; i < total; i += gridDim.x * 256) {
    int n = i & 255, kk = (i >> 8) & 31, ch = i >> 13;
    int k = ch * 32 + kk;
    dst[ch * 8192 + n * 32 + kk] = (k < K) ? (bf16)src[k * 256 + n] : (bf16)0.f;
  }
}

// ---------------------------------------------------------------------------
// ROUND-18: z + self GEMM with async B staging.
// grid (256, 4): y<2 -> z (K=576, dual-B, cols (y&1)*128); y>=2 -> self (K=64).
// B panels (the bulk: 8-16 KB/step) via global_load_lds double-buffer from
// chunk-major weights; A (2.5 KB/step) via the f32->bf16 VGPR path, also
// double-buffered, ds_write placed AFTER the MFMAs (in-order DS: writes wait
// on vmcnt, reads must not queue behind them). ONE barrier per K-step
// (was 2). Stage(next) issues before compute(cur) -- T3-minimum schedule.
// Same K-order and quantization points as before -> bit-identical output.
// ---------------------------------------------------------------------------
__global__ __launch_bounds__(256, 3) void gemm_zself(
    const float* __restrict__ x,
    const bf16* __restrict__ WtMuC, const bf16* __restrict__ WtVarC,
    const bf16* __restrict__ WtSelfC,
    const float* __restrict__ b_mu, const float* __restrict__ b_var,
    const float* __restrict__ b_self, const float* __restrict__ eps,
    bf16* __restrict__ zout, bf16* __restrict__ selfout)
{
  __shared__ bf16 lA[2][64 * 40];                  // 10240 B (padded, ds_write)
  __shared__ __align__(16) bf16 lB1[2][128 * 32];  // 16384 B (gload)
  __shared__ __align__(16) bf16 lB2[2][128 * 32];  // 16384 B (gload, z only)

  const int tid = threadIdx.x;
  const int wave = tid >> 6;
  const int lane = tid & 63;
  const int quad = lane >> 4;
  const int m = lane & 15;
  const int rowbase = blockIdx.x * 64;
  const int colbase = (blockIdx.y & 1) * 128;
  const bool isZ = blockIdx.y < 2;
  const int nch = isZ ? 18 : 2;                    // K = 576 or 64
  const bf16* __restrict__ W1 = isZ ? WtMuC : WtSelfC;
  const float* __restrict__ bias = isZ ? b_mu : b_self;

  f32x4 acc[8], accB[8];
  const f32x4 z4 = {0.f, 0.f, 0.f, 0.f};
#pragma unroll
  for (int ct = 0; ct < 8; ++ct) { acc[ct] = z4; accB[ct] = z4; }

  // A-row assignment for staging: thread p covers row p>>3, float4 seg p&7
  const int ar0 = tid >> 3, afs0 = tid & 7;
  const int ar1 = (tid + 256) >> 3, afs1 = (tid + 256) & 7;

  auto loadA = [&](int kc, int fs, int r, float4& f) {
    int k = kc + fs * 4;
    const float* src = x + (size_t)(rowbase + r) * 568 + k;
    if (k + 4 <= 568) {
      f = *(const float4*)src;
    } else {
      f.x = (k + 0 < 568) ? src[0] : 0.f;
      f.y = (k + 1 < 568) ? src[1] : 0.f;
      f.z = (k + 2 < 568) ? src[2] : 0.f;
      f.w = (k + 3 < 568) ? src[3] : 0.f;
    }
  };
  auto writeA = [&](int buf, int fs, int r, const float4& f) {
    bf16x4 o = {(bf16)f.x, (bf16)f.y, (bf16)f.z, (bf16)f.w};
    *(bf16x4*)(&lA[buf][r * 40 + fs * 4]) = o;
  };
  auto stageB = [&](int buf, int ch) {
    const bf16* s1 = W1 + (size_t)ch * 8192 + colbase * 32 + tid * 8;
    gload16(s1, &lB1[buf][wave * 512]);
    gload16(s1 + 2048, &lB1[buf][2048 + wave * 512]);
    if (isZ) {
      const bf16* s2 = WtVarC + (size_t)ch * 8192 + colbase * 32 + tid * 8;
      gload16(s2, &lB2[buf][wave * 512]);
      gload16(s2 + 2048, &lB2[buf][2048 + wave * 512]);
    }
  };

  // prologue: stage chunk 0 into buffer 0
  {
    float4 f0, f1;
    loadA(0, afs0, ar0, f0);
    loadA(0, afs1, ar1, f1);
    stageB(0, 0);
    writeA(0, afs0, ar0, f0);
    writeA(0, afs1, ar1, f1);
  }
  __syncthreads();

  for (int ch = 0; ch < nch; ++ch) {
    const int cur = ch & 1, nxt = cur ^ 1;
    float4 f0, f1;
    const bool more = (ch + 1 < nch);
    if (more) {
      stageB(nxt, ch + 1);                       // async B (vmcnt)
      loadA((ch + 1) * 32, afs0, ar0, f0);       // f32 loads (vmcnt)
      loadA((ch + 1) * 32, afs1, ar1, f1);
    }
    // compute cur (ds_reads: lgkmcnt, independent of the loads above)
    bf16x8 afrag = *(const bf16x8*)(&lA[cur][(wave * 16 + m) * 40 + quad * 8]);
#pragma unroll
    for (int ct = 0; ct < 8; ++ct) {
      bf16x8 bfrag = *(const bf16x8*)(&lB1[cur][(ct * 16 + m) * 32 + quad * 8]);
      acc[ct] = __builtin_amdgcn_mfma_f32_16x16x32_bf16(afrag, bfrag, acc[ct], 0, 0, 0);
      if (isZ) {
        bf16x8 b2 = *(const bf16x8*)(&lB2[cur][(ct * 16 + m) * 32 + quad * 8]);
        accB[ct] = __builtin_amdgcn_mfma_f32_16x16x32_bf16(afrag, b2, accB[ct], 0, 0, 0);
      }
    }
    if (more) {
      writeA(nxt, afs0, ar0, f0);                // ds_write after the ds_reads
      writeA(nxt, afs1, ar1, f1);
    }
    __syncthreads();
  }

#pragma unroll
  for (int ct = 0; ct < 8; ++ct) {
    const int col = colbase + ct * 16 + m;
    const float bv = bias[col];
#pragma unroll
    for (int r = 0; r < 4; ++r) {
      const size_t row = (size_t)rowbase + wave * 16 + quad * 4 + r;
      float v = acc[ct][r] + bv;
      if (isZ) {
        float lv = accB[ct][r] + b_var[col];
        float zz = eps[row * 256 + col] * __expf(0.5f * lv) + v;
        zout[row * 256 + col] = (bf16)zz;
      } else {
        selfout[row * 256 + col] = (bf16)(v > 0.f ? v : 0.f);
      }
    }
  }
}

// ---------------------------------------------------------------------------
// q + sv GEMM (round-15 async version, unchanged; proven).
// ---------------------------------------------------------------------------
__global__ __launch_bounds__(256, 4) void gemm_qsv(
    const bf16* __restrict__ zb, const bf16* __restrict__ selfb,
    const bf16* __restrict__ WtQc, const bf16* __restrict__ WtV2c,
    const float* __restrict__ b_q, const float* __restrict__ b_v,
    bf16* __restrict__ qout, bf16* __restrict__ svout)
{
  __shared__ __align__(16) bf16 lA[2][64 * 32];
  __shared__ __align__(16) bf16 lB[2][128 * 32];

  const int tid = threadIdx.x;
  const int wave = tid >> 6;
  const int lane = tid & 63;
  const int quad = lane >> 4;
  const int m = lane & 15;
  const int rowbase = blockIdx.x * 64;
  const int colbase = (blockIdx.y & 1) * 128;
  const bool isQ = blockIdx.y < 2;
  const bf16* __restrict__ Ap = isQ ? zb : selfb;
  const bf16* __restrict__ Wc = isQ ? WtQc : WtV2c;
  const float* __restrict__ bias = isQ ? b_q : b_v;
  bf16* __restrict__ outp = isQ ? qout : svout;

  f32x4 acc[8];
  const f32x4 z4 = {0.f, 0.f, 0.f, 0.f};
#pragma unroll
  for (int ct = 0; ct < 8; ++ct) acc[ct] = z4;

  const size_t arow = (size_t)(rowbase + (tid >> 2)) * 256 + (tid & 3) * 8;
  const size_t bbase = (size_t)colbase * 32 + (size_t)tid * 8;

  gload16(Ap + arow, &lA[0][wave * 512]);
  gload16(Wc + bbase, &lB[0][wave * 512]);
  gload16(Wc + bbase + 2048, &lB[0][2048 + wave * 512]);
  __syncthreads();

#pragma unroll
  for (int ch = 0; ch < 8; ++ch) {
    const int cur = ch & 1;
    if (ch < 7) {
      const int nxt = cur ^ 1;
      const size_t cof = (size_t)(ch + 1) * 8192;
      gload16(Ap + arow + (ch + 1) * 32, &lA[nxt][wave * 512]);
      gload16(Wc + cof + bbase, &lB[nxt][wave * 512]);
      gload16(Wc + cof + bbase + 2048, &lB[nxt][2048 + wave * 512]);
    }
    bf16x8 afrag = *(const bf16x8*)(&lA[cur][(wave * 16 + m) * 32 + quad * 8]);
#pragma unroll
    for (int ct = 0; ct < 8; ++ct) {
      bf16x8 bfrag = *(const bf16x8*)(&lB[cur][(ct * 16 + m) * 32 + quad * 8]);
      acc[ct] = __builtin_amdgcn_mfma_f32_16x16x32_bf16(afrag, bfrag, acc[ct], 0, 0, 0);
    }
    __syncthreads();
  }

#pragma unroll
  for (int ct = 0; ct < 8; ++ct) {
    const int col = colbase + ct * 16 + m;
    const float bv = bias[col];
#pragma unroll
    for (int r = 0; r < 4; ++r) {
      const size_t row = (size_t)rowbase + wave * 16 + quad * 4 + r;
      float v = acc[ct][r] + bv;
      if (isQ) v = (v > 0.f ? v : 0.f);
      outp[row * 256 + col] = (bf16)v;
    }
  }
}

// ---------------------------------------------------------------------------
// dual-A GEMM (round-15 async version, unchanged; proven).
// ---------------------------------------------------------------------------
__global__ __launch_bounds__(256, 4) void gemm_dualA(
    const bf16* __restrict__ A1, const bf16* __restrict__ A2,
    const bf16* __restrict__ Wt1c, const bf16* __restrict__ Wt2c,
    const float* __restrict__ bias, float* __restrict__ outp)
{
  __shared__ __align__(16) bf16 lA[2][64 * 32];
  __shared__ __align__(16) bf16 lB[2][128 * 32];

  const int tid = threadIdx.x;
  const int wave = tid >> 6;
  const int lane = tid & 63;
  const int quad = lane >> 4;
  const int m = lane & 15;
  const int rowbase = blockIdx.x * 64;
  const int colbase = blockIdx.y * 128;

  f32x4 acc[8];
  const f32x4 z4 = {0.f, 0.f, 0.f, 0.f};
#pragma unroll
  for (int ct = 0; ct < 8; ++ct) acc[ct] = z4;

  const size_t arow = (size_t)(rowbase + (tid >> 2)) * 256 + (tid & 3) * 8;
  const size_t bbase = (size_t)colbase * 32 + (size_t)tid * 8;

  auto stageT = [&](int buf, int t) {
    const int ch = t & 7;
    const bf16* Astep = (t < 8) ? A1 : A2;
    const bf16* Wstep = (t < 8) ? Wt1c : Wt2c;
    const size_t cof = (size_t)ch * 8192;
    gload16(Astep + arow + ch * 32, &lA[buf][wave * 512]);
    gload16(Wstep + cof + bbase, &lB[buf][wave * 512]);
    gload16(Wstep + cof + bbase + 2048, &lB[buf][2048 + wave * 512]);
  };

  stageT(0, 0);
  __syncthreads();

#pragma unroll
  for (int t = 0; t < 16; ++t) {
    const int cur = t & 1;
    if (t < 15) stageT(cur ^ 1, t + 1);
    bf16x8 afrag = *(const bf16x8*)(&lA[cur][(wave * 16 + m) * 32 + quad * 8]);
#pragma unroll
    for (int ct = 0; ct < 8; ++ct) {
      bf16x8 bfrag = *(const bf16x8*)(&lB[cur][(ct * 16 + m) * 32 + quad * 8]);
      acc[ct] = __builtin_amdgcn_mfma_f32_16x16x32_bf16(afrag, bfrag, acc[ct], 0, 0, 0);
    }
    __syncthreads();
  }

#pragma unroll
  for (int ct = 0; ct < 8; ++ct) {
    const int col = colbase + ct * 16 + m;
    const float bv = bias[col];
#pragma unroll
    for (int r = 0; r < 4; ++r) {
      const size_t row = (size_t)rowbase + wave * 16 + quad * 4 + r;
      float v = acc[ct][r] + bv;
      outp[row * 256 + col] = (v > 0.f ? v : 0.f);
    }
  }
}

// ---------------------------------------------------------------------------
// Fused attention (round-3/5 version, proven 158 us; unchanged).
// ---------------------------------------------------------------------------
__global__ __launch_bounds__(512, 4) void k_fused(
    const float* __restrict__ x, const bf16* __restrict__ qb,
    const bf16* __restrict__ svb,
    const bf16* __restrict__ WtOther, const float* __restrict__ b_other,
    const bf16* __restrict__ WtKc, const float* __restrict__ b_k,
    const bf16* __restrict__ WtVc,
    float* __restrict__ att_out, bf16* __restrict__ hb)
{
  __shared__ bf16 ldsO[80 * 264];     // 42240 B  other_em (16B-group stride 33)
  __shared__ bf16 ldsA1[80 * 40];     //  6400 B  agents tile; REUSED: spart/attl
  __shared__ bf16 qh16[1024];         //  2048 B  q (bf16); REUSED: h partials
  __shared__ bf16 svl16[1024];        //  2048 B  sv (bf16)
  float* spart = (float*)ldsA1;        // [0..320)  floats: 4 K-waves x 80 rows
  float* attl  = (float*)ldsA1 + 320;  // [320..400) floats: att weights, row order

  const int tid = threadIdx.x, wave = tid >> 6, lane = tid & 63;
  const int quad = lane >> 4, m = lane & 15;
  const int b0 = blockIdx.x * 4;
  const int kvw = wave & 3;            // column-group within K or V half
  const bool isV = wave >= 4;

  // ---- phase 0: stage q, sv (bf16 copies), agents_info (interleaved rows)
  ((unsigned*)qh16)[tid]  = ((const unsigned*)(qb  + (size_t)b0 * 256))[tid];
  ((unsigned*)svl16)[tid] = ((const unsigned*)(svb + (size_t)b0 * 256))[tid];
  for (int i = tid; i < 80 * 16; i += 512) {
    int r = i >> 4, kk = (i & 15) * 2;   // lds row r = agent*4 + batch
    int n = r >> 2, bb = r & 3;
    float v0 = 0.f, v1 = 0.f;
    if (n < 19) {
      const float* base = x + (size_t)(b0 + bb) * NOBS + 36 + n * 28;
      if (kk < 28) v0 = base[kk];
      if (kk + 1 < 28) v1 = base[kk + 1];
    }
    unsigned u0 = bfbits(v0), u1 = bfbits(v1);
    *(unsigned*)(ldsA1 + r * 40 + kk) = u0 | (u1 << 16);
  }

  const f32x4 z4 = {0.f, 0.f, 0.f, 0.f};

  // ---- issue first main-loop B buffer early (independent of all LDS)
  const bf16* __restrict__ Bc = isV ? WtVc : WtKc;
  const int cb = (kvw * 64 + m) * 32 + quad * 8;   // ((4*kvw+c)*16+m)*32+q*8 == cb+c*512
  bf16x8 bE[4];
#pragma unroll
  for (int c = 0; c < 4; ++c) bE[c] = *(const bf16x8*)(Bc + cb + c * 512);

  __syncthreads();

  // ---- phase 1: other_em = relu(A1 @ WtOther^T + b_other), K=32.
  {
    float bo[2];
    bf16x8 bfr[2];
#pragma unroll
    for (int c = 0; c < 2; ++c) {
      int col = (2 * wave + c) * 16 + m;
      bo[c] = b_other[col];
      bfr[c] = *(const bf16x8*)(WtOther + col * 32 + quad * 8);
    }
    f32x4 acc1[5][2];
#pragma unroll
    for (int rt = 0; rt < 5; ++rt) {
      bf16x8 a = *(const bf16x8*)(ldsA1 + (rt * 16 + m) * 40 + quad * 8);
#pragma unroll
      for (int c = 0; c < 2; ++c)
        acc1[rt][c] = __builtin_amdgcn_mfma_f32_16x16x32_bf16(a, bfr[c], z4, 0, 0, 0);
    }
#pragma unroll
    for (int rt = 0; rt < 5; ++rt)
#pragma unroll
      for (int c = 0; c < 2; ++c) {
        int col = (2 * wave + c) * 16 + m;
#pragma unroll
        for (int r = 0; r < 4; ++r) {
          float v = acc1[rt][c][r] + bo[c];
          v = v > 0.f ? v : 0.f;
          unsigned u = bfbits(v);
          unsigned other = (unsigned)__shfl_xor((int)u, 1, 64);
          if ((m & 1) == 0) {
            int rowl = rt * 16 + quad * 4 + r;
            *(unsigned*)(ldsO + rowl * 264 + col) = u | (other << 16);
          }
        }
      }
  }
  __syncthreads();   // ldsA1 (agents tile) dead from here; spart/attl overlay

  // ---- unified main GEMM: 80 rows x 512 cols ([WtK | WtV]), 8 chunks,
  // ping-pong software pipeline (prefetch distance 1, no conditionals).
  f32x4 acc[5][4];
#pragma unroll
  for (int rt = 0; rt < 5; ++rt)
#pragma unroll
    for (int c = 0; c < 4; ++c) acc[rt][c] = z4;

  {
#pragma unroll 1
    for (int ch = 0; ch < 8; ch += 2) {
      bf16x8 bO[4];
#pragma unroll
      for (int c = 0; c < 4; ++c)
        bO[c] = *(const bf16x8*)(Bc + (size_t)(ch + 1) * 8192 + cb + c * 512);
      const int kc0 = ch * 32;
#pragma unroll
      for (int rt = 0; rt < 5; ++rt) {
        bf16x8 a = *(const bf16x8*)(ldsO + (rt * 16 + m) * 264 + kc0 + quad * 8);
#pragma unroll
        for (int c = 0; c < 4; ++c)
          acc[rt][c] = __builtin_amdgcn_mfma_f32_16x16x32_bf16(a, bE[c], acc[rt][c], 0, 0, 0);
      }
      // prefetch ch+2; at ch==6 this reads chunk 8 = adjacent weight region
#pragma unroll
      for (int c = 0; c < 4; ++c)
        bE[c] = *(const bf16x8*)(Bc + (size_t)(ch + 2) * 8192 + cb + c * 512);
      const int kc1 = kc0 + 32;
#pragma unroll
      for (int rt = 0; rt < 5; ++rt) {
        bf16x8 a = *(const bf16x8*)(ldsO + (rt * 16 + m) * 264 + kc1 + quad * 8);
#pragma unroll
        for (int c = 0; c < 4; ++c)
          acc[rt][c] = __builtin_amdgcn_mfma_f32_16x16x32_bf16(a, bO[c], acc[rt][c], 0, 0, 0);
      }
    }
  }

  // ---- K-waves: scores = (relu(k)+b_k) . q, reduce over lanes -> spart
  if (!isV) {
    float qreg[4][4], bkreg[4];
#pragma unroll
    for (int c = 0; c < 4; ++c) {
      int col = (4 * wave + c) * 16 + m;
      bkreg[c] = b_k[col];
#pragma unroll
      for (int r = 0; r < 4; ++r) qreg[c][r] = (float)qh16[r * 256 + col];
    }
#pragma unroll
    for (int rt = 0; rt < 5; ++rt) {
      float part[4] = {0.f, 0.f, 0.f, 0.f};
#pragma unroll
      for (int c = 0; c < 4; ++c) {
#pragma unroll
        for (int r = 0; r < 4; ++r) {
          float kv = acc[rt][c][r] + bkreg[c];
          kv = kv > 0.f ? kv : 0.f;
          part[r] += kv * qreg[c][r];
        }
      }
#pragma unroll
      for (int r = 0; r < 4; ++r) {
        float p = part[r];
        p += __shfl_xor(p, 1, 64);
        p += __shfl_xor(p, 2, 64);
        p += __shfl_xor(p, 4, 64);
        p += __shfl_xor(p, 8, 64);
        if (m == 0) spart[wave * 80 + rt * 16 + quad * 4 + r] = p;
      }
    }
  }
  __syncthreads();

  // ---- softmax: wave w = batch w, lanes 0-18 = agents (width-32 tree)
  if (!isV && lane < 32) {
    const int bb = wave, j = lane;      // batch, agent
    float s = -1e30f;
    if (j < 19) {
      int row = j * 4 + bb;             // interleaved: row = agent*4 + batch
      s = (spart[row] + spart[80 + row] + spart[160 + row] + spart[240 + row]) * 0.0625f;
    }
    float mx = s;
#pragma unroll
    for (int off = 16; off >= 1; off >>= 1) mx = fmaxf(mx, __shfl_xor(mx, off, 32));
    float e = (j < 19) ? __expf(s - mx) : 0.f;
    float sum = e;
#pragma unroll
    for (int off = 16; off >= 1; off >>= 1) sum += __shfl_xor(sum, off, 32);
    float inv = 1.f / sum;
    float a = e * inv;
    if (j < 20) attl[j * 4 + bb] = a;   // j==19 writes the zero pad row
    if (j < 19) att_out[(size_t)(b0 + bb) * 19 + j] = a;
  }
  __syncthreads();

  // ---- V-waves: epilogue  h = sum_rows att * relu(v + sv)
  if (isV) {
    float svreg[4][4];
#pragma unroll
    for (int c = 0; c < 4; ++c) {
      int col = (4 * kvw + c) * 16 + m;
#pragma unroll
      for (int r = 0; r < 4; ++r) svreg[c][r] = (float)svl16[r * 256 + col];
    }
    float hacc[4][4];   // [c][batch==r]
#pragma unroll
    for (int c = 0; c < 4; ++c)
#pragma unroll
      for (int r = 0; r < 4; ++r) hacc[c][r] = 0.f;
#pragma unroll
    for (int rt = 0; rt < 5; ++rt) {
      float av[4];
#pragma unroll
      for (int r = 0; r < 4; ++r) av[r] = attl[rt * 16 + quad * 4 + r];
#pragma unroll
      for (int c = 0; c < 4; ++c) {
#pragma unroll
        for (int r = 0; r < 4; ++r) {
          float v = acc[rt][c][r] + svreg[c][r];
          v = v > 0.f ? v : 0.f;
          hacc[c][r] += v * av[r];
        }
      }
    }
#pragma unroll
    for (int c = 0; c < 4; ++c)
#pragma unroll
      for (int r = 0; r < 4; ++r) {
        float h = hacc[c][r];
        h += __shfl_xor(h, 16, 64);
        h += __shfl_xor(h, 32, 64);
        if (quad == 0) qh16[r * 256 + (4 * kvw + c) * 16 + m] = (bf16)h;
      }
  }
  __syncthreads();
  ((unsigned*)(hb + (size_t)b0 * 256))[tid] = ((const unsigned*)qh16)[tid];
}

// ---------------------------------------------------------------------------
extern "C" void kernel_launch(void* const* d_in, const int* in_sizes, int n_in,
                              void* d_out, int out_size, void* d_ws, size_t ws_size,
                              hipStream_t stream) {
  (void)in_sizes; (void)n_in; (void)out_size; (void)ws_size;
  const float* x      = (const float*)d_in[0];
  const float* eps    = (const float*)d_in[1];
  const float* W_mu   = (const float*)d_in[2];
  const float* b_mu   = (const float*)d_in[3];
  const float* W_var  = (const float*)d_in[4];
  const float* b_var  = (const float*)d_in[5];
  const float* W_self = (const float*)d_in[6];
  const float* b_self = (const float*)d_in[7];
  const float* W_other= (const float*)d_in[8];
  const float* b_other= (const float*)d_in[9];
  const float* W_q    = (const float*)d_in[10];
  const float* b_q    = (const float*)d_in[11];
  const float* W_k    = (const float*)d_in[12];
  const float* b_k    = (const float*)d_in[13];
  const float* W_v    = (const float*)d_in[14];
  const float* b_v    = (const float*)d_in[15];
  const float* W_a    = (const float*)d_in[16];
  const float* b_a    = (const float*)d_in[17];

  char* wsb = (char*)d_ws;
  bf16* WtMu    = (bf16*)(wsb + OFF_WT_MU);
  bf16* WtVar   = (bf16*)(wsb + OFF_WT_VAR);
  bf16* WtSelf  = (bf16*)(wsb + OFF_WT_SELF);
  bf16* WtOther = (bf16*)(wsb + OFF_WT_OTHER);
  bf16* WtQ     = (bf16*)(wsb + OFF_WT_Q);
  bf16* WtK     = (bf16*)(wsb + OFF_WT_K);
  bf16* WtV1    = (bf16*)(wsb + OFF_WT_V1);
  bf16* WtV2    = (bf16*)(wsb + OFF_WT_V2);
  bf16* WtA1    = (bf16*)(wsb + OFF_WT_A1);
  bf16* WtA2    = (bf16*)(wsb + OFF_WT_A2);
  bf16* zbuf    = (bf16*)(wsb + OFF_Z);
  bf16* selfbuf = (bf16*)(wsb + OFF_SELF);
  bf16* qbuf    = (bf16*)(wsb + OFF_Q);
  bf16* svbuf   = (bf16*)(wsb + OFF_SV);
  bf16* hbuf    = (bf16*)(wsb + OFF_H);

  float* out = (float*)d_out;
  float* att_out = out + (size_t)NB * 256;

  dim3 blk(256);
  wprep<<<dim3(160, 10), blk, 0, stream>>>(W_mu, W_var, W_self, W_other, W_q, W_k, W_v, W_a, wsb);
  // z = eps*exp(0.5*logvar)+mu  AND  self_em = relu(x@W_self+b), async-B staged
  gemm_zself<<<dim3(NB / 64, 4), blk, 0, stream>>>(x, WtMu, WtVar, WtSelf,
                                                   b_mu, b_var, b_self, eps, zbuf, selfbuf);
  // q = relu(z@W_q+b_q)  AND  sv = self_em@W_v[256:]+b_v, one launch (async)
  gemm_qsv<<<dim3(NB / 64, 4), blk, 0, stream>>>(zbuf, selfbuf, WtQ, WtV2,
                                                 b_q, b_v, qbuf, svbuf);
  // fused: other_em -> [k | v] unified GEMM -> scores -> softmax -> h
  k_fused<<<NB / 4, dim3(512), 0, stream>>>(x, qbuf, svbuf, WtOther, b_other, WtK, b_k,
                                            WtV1, att_out, hbuf);
  // out = relu([h; self_em] @ W_a + b_a)   (dual-A, async staged)
  gemm_dualA<<<dim3(NB / 64, 2), blk, 0, stream>>>(hbuf, selfbuf, WtA1, WtA2, b_a, out);
}